// Round 14
// baseline (121.483 us; speedup 1.0000x reference)
//
#include <hip/hip_runtime.h>
#include <hip/hip_bf16.h>

// Problem constants
constexpr int BATCH = 4;
constexpr int NSEQ  = 1024;
constexpr int CDIM  = 768;
constexpr int NHEAD = 12;
constexpr int HDIM  = 64;
constexpr int MTOT  = BATCH * NSEQ;   // 4096
constexpr int QKVN  = 3 * CDIM;       // 2304
constexpr int NBH   = BATCH * NHEAD;  // 48

typedef __bf16 bf16x8 __attribute__((ext_vector_type(8)));
typedef float  f32x4  __attribute__((ext_vector_type(4)));

__device__ __forceinline__ unsigned short f2bf(float f) {
    unsigned u = __builtin_bit_cast(unsigned, f);
    unsigned r = u + 0x7FFFu + ((u >> 16) & 1u);   // RNE
    return (unsigned short)(r >> 16);
}
__device__ __forceinline__ float bf2f(unsigned short h) {
    unsigned u = ((unsigned)h) << 16;
    return __builtin_bit_cast(float, u);
}
// pack two f32 -> two bf16 in one dword (pure VALU; r9-verified)
__device__ __forceinline__ unsigned pack_bf16(float lo, float hi) {
    return (unsigned)f2bf(lo) | ((unsigned)f2bf(hi) << 16);
}

#define GLOAD_LDS16(gp, lp)                                                    \
    __builtin_amdgcn_global_load_lds(                                          \
        (const __attribute__((address_space(1))) void*)(gp),                   \
        (__attribute__((address_space(3))) void*)(lp), 16, 0, 0)

// ---------------------------------------------------------------------------
// Prologue converts
// ---------------------------------------------------------------------------
__global__ __launch_bounds__(256) void cvt_f32_bf16(
    const float* __restrict__ in, unsigned short* __restrict__ out, int n4)
{
    int i = blockIdx.x * 256 + threadIdx.x;
    if (i < n4) {
        float4 a = reinterpret_cast<const float4*>(in)[i];
        ushort4 h;
        h.x = f2bf(a.x); h.y = f2bf(a.y); h.z = f2bf(a.z); h.w = f2bf(a.w);
        reinterpret_cast<ushort4*>(out)[i] = h;
    }
}

// in [R][C] f32  ->  out [C][R] bf16  (32x32 tiles)
__global__ __launch_bounds__(256) void tcvt_f32_bf16(
    const float* __restrict__ in, unsigned short* __restrict__ out, int R, int C)
{
    __shared__ unsigned short t[32][33];
    const int c0 = blockIdx.x * 32, r0 = blockIdx.y * 32;
    const int tc = threadIdx.x & 31, tr = threadIdx.x >> 5;  // tr 0..7
    #pragma unroll
    for (int i = 0; i < 4; i++)
        t[tc][tr + 8 * i] = f2bf(in[(size_t)(r0 + tr + 8 * i) * C + c0 + tc]);
    __syncthreads();
    #pragma unroll
    for (int i = 0; i < 4; i++)
        out[(size_t)(c0 + tr + 8 * i) * R + r0 + tc] = t[tr + 8 * i][tc];
}

// ---------------------------------------------------------------------------
// QKV GEMM: xb [4096,768] bf16 @ wt [2304,768] bf16 (pre-transposed) + bias
// -> Q*0.125 [B,H,N,64]; K [B,H,N,64] with rows PERMUTED within 32-row
// groups (bits 4..2 rotated: s' = (s&0x3E3)|((s&4)<<2)|((s&0x18)>>1)) so the
// attention kernel's linear global_load_lds staging yields the lane-local
// S^T -> PV alignment (r9-verified sigma); Vt [B,H,64,N] unpermuted.
// ---------------------------------------------------------------------------
__global__ __launch_bounds__(256) void qkv_gemm(
    const unsigned short* __restrict__ xb,   // [4096][768]
    const unsigned short* __restrict__ wt,   // [2304][768]
    const float* __restrict__ bias,
    unsigned short* __restrict__ qbuf, unsigned short* __restrict__ kbuf,
    unsigned short* __restrict__ vtbuf)
{
    __shared__ unsigned short As[128 * 32];
    __shared__ unsigned short Bs[128 * 32];
    const int tid  = threadIdx.x;
    const int lane = tid & 63;
    const int wid  = tid >> 6;
    const int wm = (wid >> 1) * 64, wn = (wid & 1) * 64;
    const int g = lane >> 4, li = lane & 15;
    const int m0 = blockIdx.y * 128;
    const int n0 = blockIdx.x * 128;
    const int srow = lane >> 2;
    const int scol = (lane & 3) * 8;

    f32x4 acc[4][4];
    #pragma unroll
    for (int i = 0; i < 4; i++)
        #pragma unroll
        for (int j = 0; j < 4; j++) acc[i][j] = f32x4{0.f, 0.f, 0.f, 0.f};

    for (int k0 = 0; k0 < CDIM; k0 += 32) {
        __syncthreads();
        #pragma unroll
        for (int c = 0; c < 2; c++) {
            int row = wid * 32 + c * 16 + srow;
            GLOAD_LDS16(&xb[(size_t)(m0 + row) * CDIM + k0 + scol],
                        &As[(wid * 32 + c * 16) * 32]);
            GLOAD_LDS16(&wt[(size_t)(n0 + row) * CDIM + k0 + scol],
                        &Bs[(wid * 32 + c * 16) * 32]);
        }
        __syncthreads();
        bf16x8 a[4], b[4];
        #pragma unroll
        for (int mt = 0; mt < 4; mt++)
            a[mt] = *reinterpret_cast<const bf16x8*>(&As[(wm + 16 * mt + li) * 32 + 8 * g]);
        #pragma unroll
        for (int nt = 0; nt < 4; nt++)
            b[nt] = *reinterpret_cast<const bf16x8*>(&Bs[(wn + 16 * nt + li) * 32 + 8 * g]);
        #pragma unroll
        for (int mt = 0; mt < 4; mt++)
            #pragma unroll
            for (int nt = 0; nt < 4; nt++)
                acc[mt][nt] = __builtin_amdgcn_mfma_f32_16x16x32_bf16(a[mt], b[nt], acc[mt][nt], 0, 0, 0);
    }

    #pragma unroll
    for (int mt = 0; mt < 4; mt++) {
        #pragma unroll
        for (int nt = 0; nt < 4; nt++) {
            int col  = n0 + wn + 16 * nt + li;
            int tsel = col / CDIM;
            int rem  = col - tsel * CDIM;
            int h_ = rem >> 6, d = rem & 63;
            float bv = bias[col];
            float sc = (tsel == 0) ? 0.125f : 1.0f;
            #pragma unroll
            for (int r = 0; r < 4; r++) {
                int m  = m0 + wm + 16 * mt + 4 * g + r;
                int b_ = m >> 10, s = m & 1023;
                unsigned short hv = f2bf((acc[mt][nt][r] + bv) * sc);
                if (tsel == 0)
                    qbuf[(((size_t)b_ * NHEAD + h_) * NSEQ + s) * HDIM + d] = hv;
                else if (tsel == 1) {
                    int sp = (s & 0x3E3) | ((s & 4) << 2) | ((s & 0x18) >> 1);
                    kbuf[(((size_t)b_ * NHEAD + h_) * NSEQ + sp) * HDIM + d] = hv;
                } else
                    vtbuf[(((size_t)b_ * NHEAD + h_) * HDIM + d) * NSEQ + s] = hv;
            }
        }
    }
}

// ---------------------------------------------------------------------------
// Flash-style attention, no-max softmax, KV-SPLIT=2 (additive partials).
// grid (16 qtiles, 48 bh, 2 halves); each block: 512 keys = 8 tiles of 64.
// Async double-buffered K/V via global_load_lds (r10) + lane-local P via
// permuted kbuf + swapped QK^T (r9) -> NO Ps LDS: 32KB LDS = exactly
// 5 blocks/CU. Partial O (bf16, unnormalized) + partial l (f32) to ws;
// combine kernel sums halves and normalizes (softmax has no max-tracking,
// so partials are purely additive).
// ---------------------------------------------------------------------------
__global__ __launch_bounds__(256, 5) void attn_kernel(
    const unsigned short* __restrict__ qbuf,
    const unsigned short* __restrict__ kbuf,   // row-permuted
    const unsigned short* __restrict__ vtbuf,
    const float* __restrict__ bias,            // [H,N,N]
    unsigned short* __restrict__ osplit,       // [2][48*1024*64] bf16
    float* __restrict__ lsplit)                // [2][48*1024] f32
{
    __shared__ unsigned short Kl[2][64 * 64];  // [pos][d] linear, src-swizzled
    __shared__ unsigned short Vl[2][64 * 64];  // V^T [d][k] linear, swizzled

    const int tid  = threadIdx.x;
    const int lane = tid & 63;
    const int wid  = tid >> 6;
    const int g = lane >> 4, li = lane & 15;
    const int srow8 = lane >> 3;               // 0..7
    const int scs8  = (lane & 7) ^ srow8;      // swizzled source slot
    const int bh = blockIdx.y;
    const int b_ = bh / NHEAD, h_ = bh % NHEAD;
    const int qw = blockIdx.x * 64 + wid * 16;
    const int z  = blockIdx.z;                 // KV half
    const int t0 = z * 8;                      // first tile of this half

    const unsigned short* qb = qbuf + (size_t)bh * NSEQ * HDIM;
    const unsigned short* kb = kbuf + (size_t)bh * NSEQ * HDIM;
    const unsigned short* vb = vtbuf + (size_t)bh * HDIM * NSEQ;
    const float* bb = bias + (size_t)h_ * NSEQ * NSEQ;
    unsigned short* osz = osplit + (size_t)z * NBH * NSEQ * HDIM;
    float* lsz = lsplit + (size_t)z * NBH * NSEQ;

#define STAGE(T, KL, VL)                                                       \
    {                                                                          \
        _Pragma("unroll") for (int i = 0; i < 2; i++) {                        \
            GLOAD_LDS16(kb + (size_t)((T) * 64 + wid * 16 + i * 8 + srow8) * HDIM + scs8 * 8, \
                        (KL) + (wid * 16 + i * 8) * 64);                       \
            GLOAD_LDS16(vb + (size_t)(wid * 16 + i * 8 + srow8) * NSEQ + (T) * 64 + scs8 * 8, \
                        (VL) + (wid * 16 + i * 8) * 64);                       \
        }                                                                      \
    }

    // one 64-key tile: swapped QK^T on permuted-K positions -> lane-local P
    // (lane (g,li): q=li, keys slab*32 + 8g + 0..7), pack, PV. K0 = key base.
#define COMPUTE(KS, VS, K0)                                                    \
    {                                                                          \
        const float* bp = &bb[(size_t)(qw + li) * NSEQ + (K0) + 8 * g];        \
        f32x4 b00 = *reinterpret_cast<const f32x4*>(bp);                       \
        f32x4 b01 = *reinterpret_cast<const f32x4*>(bp + 4);                   \
        f32x4 b10 = *reinterpret_cast<const f32x4*>(bp + 32);                  \
        f32x4 b11 = *reinterpret_cast<const f32x4*>(bp + 36);                  \
        _Pragma("unroll") for (int sl = 0; sl < 2; sl++) {                     \
            f32x4 s0 = f32x4{0.f, 0.f, 0.f, 0.f};                              \
            f32x4 s1 = f32x4{0.f, 0.f, 0.f, 0.f};                              \
            _Pragma("unroll") for (int dd = 0; dd < 2; dd++) {                 \
                bf16x8 kf0 = *reinterpret_cast<const bf16x8*>(                 \
                    (KS) + (32 * sl + li) * 64 + (((4 * dd + g) ^ (li & 7)) * 8)); \
                bf16x8 kf1 = *reinterpret_cast<const bf16x8*>(                 \
                    (KS) + (32 * sl + 16 + li) * 64 + (((4 * dd + g) ^ (li & 7)) * 8)); \
                s0 = __builtin_amdgcn_mfma_f32_16x16x32_bf16(kf0, qf[dd], s0, 0, 0, 0); \
                s1 = __builtin_amdgcn_mfma_f32_16x16x32_bf16(kf1, qf[dd], s1, 0, 0, 0); \
            }                                                                  \
            f32x4 blo = sl ? b10 : b00;                                        \
            f32x4 bhi = sl ? b11 : b01;                                        \
            float p0 = __expf(s0[0] + blo[0]);                                 \
            float p1 = __expf(s0[1] + blo[1]);                                 \
            float p2 = __expf(s0[2] + blo[2]);                                 \
            float p3 = __expf(s0[3] + blo[3]);                                 \
            float p4 = __expf(s1[0] + bhi[0]);                                 \
            float p5 = __expf(s1[1] + bhi[1]);                                 \
            float p6 = __expf(s1[2] + bhi[2]);                                 \
            float p7 = __expf(s1[3] + bhi[3]);                                 \
            lpart += ((p0 + p1) + (p2 + p3)) + ((p4 + p5) + (p6 + p7));        \
            uint4 pw;                                                          \
            pw.x = pack_bf16(p0, p1);                                          \
            pw.y = pack_bf16(p2, p3);                                          \
            pw.z = pack_bf16(p4, p5);                                          \
            pw.w = pack_bf16(p6, p7);                                          \
            bf16x8 pf = __builtin_bit_cast(bf16x8, pw);                        \
            _Pragma("unroll") for (int dt = 0; dt < 4; dt++) {                 \
                bf16x8 vf = *reinterpret_cast<const bf16x8*>(                  \
                    (VS) + (16 * dt + li) * 64 + (((4 * sl + g) ^ (li & 7)) * 8)); \
                oacc[dt] = __builtin_amdgcn_mfma_f32_16x16x32_bf16(pf, vf, oacc[dt], 0, 0, 0); \
            }                                                                  \
        }                                                                      \
    }

    bf16x8 qf[2];
    #pragma unroll
    for (int dd = 0; dd < 2; dd++)
        qf[dd] = *reinterpret_cast<const bf16x8*>(&qb[(size_t)(qw + li) * HDIM + 32 * dd + 8 * g]);

    f32x4 oacc[4];
    #pragma unroll
    for (int dt = 0; dt < 4; dt++) oacc[dt] = f32x4{0.f, 0.f, 0.f, 0.f};
    float lpart = 0.f;   // partial denominator for q = qw + li

    STAGE(t0, Kl[0], Vl[0]);
    __syncthreads();

    for (int j = 0; j < 4; ++j) {
        const int tA = t0 + 2 * j;
        STAGE(tA + 1, Kl[1], Vl[1]);
        COMPUTE(Kl[0], Vl[0], tA * 64);
        __syncthreads();
        if (j < 3) STAGE(tA + 2, Kl[0], Vl[0]);
        COMPUTE(Kl[1], Vl[1], (tA + 1) * 64);
        __syncthreads();
    }

    // partial l: sum over g groups -> lane li holds l[qw+li]
    lpart += __shfl_xor(lpart, 16);
    lpart += __shfl_xor(lpart, 32);
    if (lane < 16)
        lsz[(size_t)bh * NSEQ + qw + lane] = lpart;

    // partial O (unnormalized) bf16
    #pragma unroll
    for (int dt = 0; dt < 4; dt++)
        #pragma unroll
        for (int r = 0; r < 4; r++) {
            int sq = qw + 4 * g + r;
            osz[((size_t)bh * NSEQ + sq) * HDIM + 16 * dt + li] = f2bf(oacc[dt][r]);
        }
#undef STAGE
#undef COMPUTE
}

// ---------------------------------------------------------------------------
// Combine: y = (O0+O1)/(l0+l1), write bf16 [B,N,C] (col = h*64+d)
// ---------------------------------------------------------------------------
__global__ __launch_bounds__(256) void combine_kernel(
    const unsigned short* __restrict__ osplit,  // [2][48*1024*64]
    const float* __restrict__ lsplit,           // [2][48*1024]
    unsigned short* __restrict__ ybuf)          // [B,N,C]
{
    const int tid = threadIdx.x;
    const int row = blockIdx.x * 16 + (tid >> 4);   // 0..49151 = bh*1024+q
    const int d0  = (tid & 15) * 4;
    const size_t HALF_O = (size_t)NBH * NSEQ * HDIM;
    const size_t HALF_L = (size_t)NBH * NSEQ;

    float l = lsplit[row] + lsplit[HALF_L + row];
    float inv = 1.f / l;
    ushort4 a = *reinterpret_cast<const ushort4*>(&osplit[(size_t)row * HDIM + d0]);
    ushort4 b = *reinterpret_cast<const ushort4*>(&osplit[HALF_O + (size_t)row * HDIM + d0]);
    ushort4 o;
    o.x = f2bf((bf2f(a.x) + bf2f(b.x)) * inv);
    o.y = f2bf((bf2f(a.y) + bf2f(b.y)) * inv);
    o.z = f2bf((bf2f(a.z) + bf2f(b.z)) * inv);
    o.w = f2bf((bf2f(a.w) + bf2f(b.w)) * inv);

    int bh = row >> 10, q = row & 1023;
    int b_ = bh / NHEAD, h_ = bh % NHEAD;
    *reinterpret_cast<ushort4*>(
        &ybuf[((size_t)b_ * NSEQ + q) * CDIM + h_ * HDIM + d0]) = o;
}

// ---------------------------------------------------------------------------
// Proj GEMM: ybuf [4096,768] bf16 @ pwt [768,768] bf16 (pre-transposed)
// + proj_b -> fp32 out.
// ---------------------------------------------------------------------------
__global__ __launch_bounds__(256) void proj_gemm(
    const unsigned short* __restrict__ yb,   // [4096][768]
    const unsigned short* __restrict__ pwt,  // [768][768] (n,k)
    const float* __restrict__ bias, float* __restrict__ out)
{
    __shared__ unsigned short As[128 * 32];
    __shared__ unsigned short Bs[128 * 32];
    const int tid  = threadIdx.x;
    const int lane = tid & 63;
    const int wid  = tid >> 6;
    const int wm = (wid >> 1) * 64, wn = (wid & 1) * 64;
    const int g = lane >> 4, li = lane & 15;
    const int m0 = blockIdx.y * 128;
    const int n0 = blockIdx.x * 128;
    const int srow = lane >> 2;
    const int scol = (lane & 3) * 8;

    f32x4 acc[4][4];
    #pragma unroll
    for (int i = 0; i < 4; i++)
        #pragma unroll
        for (int j = 0; j < 4; j++) acc[i][j] = f32x4{0.f, 0.f, 0.f, 0.f};

    for (int k0 = 0; k0 < CDIM; k0 += 32) {
        __syncthreads();
        #pragma unroll
        for (int c = 0; c < 2; c++) {
            int row = wid * 32 + c * 16 + srow;
            GLOAD_LDS16(&yb[(size_t)(m0 + row) * CDIM + k0 + scol],
                        &As[(wid * 32 + c * 16) * 32]);
            GLOAD_LDS16(&pwt[(size_t)(n0 + row) * CDIM + k0 + scol],
                        &Bs[(wid * 32 + c * 16) * 32]);
        }
        __syncthreads();
        bf16x8 a[4], b[4];
        #pragma unroll
        for (int mt = 0; mt < 4; mt++)
            a[mt] = *reinterpret_cast<const bf16x8*>(&As[(wm + 16 * mt + li) * 32 + 8 * g]);
        #pragma unroll
        for (int nt = 0; nt < 4; nt++)
            b[nt] = *reinterpret_cast<const bf16x8*>(&Bs[(wn + 16 * nt + li) * 32 + 8 * g]);
        #pragma unroll
        for (int mt = 0; mt < 4; mt++)
            #pragma unroll
            for (int nt = 0; nt < 4; nt++)
                acc[mt][nt] = __builtin_amdgcn_mfma_f32_16x16x32_bf16(a[mt], b[nt], acc[mt][nt], 0, 0, 0);
    }

    #pragma unroll
    for (int mt = 0; mt < 4; mt++)
        #pragma unroll
        for (int nt = 0; nt < 4; nt++) {
            int col = n0 + wn + 16 * nt + li;
            float bv = bias[col];
            #pragma unroll
            for (int r = 0; r < 4; r++) {
                int m = m0 + wm + 16 * mt + 4 * g + r;
                out[(size_t)m * CDIM + col] = acc[mt][nt][r] + bv;
            }
        }
}

extern "C" void kernel_launch(void* const* d_in, const int* in_sizes, int n_in,
                              void* d_out, int out_size, void* d_ws, size_t ws_size,
                              hipStream_t stream) {
    const float* x         = (const float*)d_in[0];
    const float* attn_bias = (const float*)d_in[1];
    const float* qkv_w     = (const float*)d_in[2];
    const float* qkv_b     = (const float*)d_in[3];
    const float* proj_w    = (const float*)d_in[4];
    const float* proj_b    = (const float*)d_in[5];
    float* out = (float*)d_out;

    const size_t per = (size_t)NBH * NSEQ * HDIM;  // 3,145,728
    unsigned short* qbuf  = (unsigned short*)d_ws;
    unsigned short* kbuf  = qbuf + per;
    unsigned short* vtbuf = kbuf + per;
    unsigned short* xb    = vtbuf + per;
    unsigned short* qwt   = xb + per;                    // [2304][768]
    unsigned short* pwt   = qwt + (size_t)QKVN * CDIM;   // [768][768]
    unsigned short* osplit = pwt + (size_t)CDIM * CDIM;  // [2][per] bf16
    float* lsplit = (float*)(osplit + 2 * per);          // [2][48*1024] f32
    unsigned short* ybuf  = xb;  // x dead after qkv_gemm

    cvt_f32_bf16<<<(MTOT * CDIM / 4 + 255) / 256, 256, 0, stream>>>(
        x, xb, MTOT * CDIM / 4);
    tcvt_f32_bf16<<<dim3(QKVN / 32, CDIM / 32), 256, 0, stream>>>(
        qkv_w, qwt, CDIM, QKVN);
    tcvt_f32_bf16<<<dim3(CDIM / 32, CDIM / 32), 256, 0, stream>>>(
        proj_w, pwt, CDIM, CDIM);

    qkv_gemm<<<dim3(QKVN / 128, MTOT / 128), 256, 0, stream>>>(
        xb, qwt, qkv_b, qbuf, kbuf, vtbuf);
    attn_kernel<<<dim3(NSEQ / 64, NBH, 2), 256, 0, stream>>>(
        qbuf, kbuf, vtbuf, attn_bias, osplit, lsplit);
    combine_kernel<<<NBH * NSEQ / 16, 256, 0, stream>>>(
        osplit, lsplit, ybuf);
    proj_gemm<<<dim3(CDIM / 128, MTOT / 128), 256, 0, stream>>>(
        ybuf, pwt, proj_b, out);
}

// Round 15
// 107.289 us; speedup vs baseline: 1.1323x; 1.1323x over previous
//
#include <hip/hip_runtime.h>
#include <hip/hip_bf16.h>

// Problem constants
constexpr int BATCH = 4;
constexpr int NSEQ  = 1024;
constexpr int CDIM  = 768;
constexpr int NHEAD = 12;
constexpr int HDIM  = 64;
constexpr int MTOT  = BATCH * NSEQ;   // 4096
constexpr int QKVN  = 3 * CDIM;       // 2304

typedef __bf16 bf16x8 __attribute__((ext_vector_type(8)));
typedef float  f32x4  __attribute__((ext_vector_type(4)));

__device__ __forceinline__ unsigned short f2bf(float f) {
    unsigned u = __builtin_bit_cast(unsigned, f);
    unsigned r = u + 0x7FFFu + ((u >> 16) & 1u);   // RNE
    return (unsigned short)(r >> 16);
}

#define GLOAD_LDS16(gp, lp)                                                    \
    __builtin_amdgcn_global_load_lds(                                          \
        (const __attribute__((address_space(1))) void*)(gp),                   \
        (__attribute__((address_space(3))) void*)(lp), 16, 0, 0)

// ---------------------------------------------------------------------------
// Prologue converts
// ---------------------------------------------------------------------------
__global__ __launch_bounds__(256) void cvt_f32_bf16(
    const float* __restrict__ in, unsigned short* __restrict__ out, int n4)
{
    int i = blockIdx.x * 256 + threadIdx.x;
    if (i < n4) {
        float4 a = reinterpret_cast<const float4*>(in)[i];
        ushort4 h;
        h.x = f2bf(a.x); h.y = f2bf(a.y); h.z = f2bf(a.z); h.w = f2bf(a.w);
        reinterpret_cast<ushort4*>(out)[i] = h;
    }
}

// in [R][C] f32  ->  out [C][R] bf16  (32x32 tiles)
__global__ __launch_bounds__(256) void tcvt_f32_bf16(
    const float* __restrict__ in, unsigned short* __restrict__ out, int R, int C)
{
    __shared__ unsigned short t[32][33];
    const int c0 = blockIdx.x * 32, r0 = blockIdx.y * 32;
    const int tc = threadIdx.x & 31, tr = threadIdx.x >> 5;  // tr 0..7
    #pragma unroll
    for (int i = 0; i < 4; i++)
        t[tc][tr + 8 * i] = f2bf(in[(size_t)(r0 + tr + 8 * i) * C + c0 + tc]);
    __syncthreads();
    #pragma unroll
    for (int i = 0; i < 4; i++)
        out[(size_t)(c0 + tr + 8 * i) * R + r0 + tc] = t[tr + 8 * i][tc];
}

// ---------------------------------------------------------------------------
// QKV GEMM: xb [4096,768] bf16 @ wt [2304,768] bf16 (pre-transposed) + bias
// -> scatter bf16 into Q*0.125 [B,H,N,64], K [B,H,N,64], Vt [B,H,64,N]
// BK=64 (12 barrier-drains instead of 24 — the m97 ceiling stall) with the
// attn-proven XOR source-swizzle: 128B LDS rows would be 16-way conflicted;
// slot s of row r stored at s^(r&7), frag reads XOR identically.
// LDS 32KB -> capacity 5 blocks/CU >= grid 2.25.
// ---------------------------------------------------------------------------
__global__ __launch_bounds__(256) void qkv_gemm(
    const unsigned short* __restrict__ xb,   // [4096][768]
    const unsigned short* __restrict__ wt,   // [2304][768]
    const float* __restrict__ bias,
    unsigned short* __restrict__ qbuf, unsigned short* __restrict__ kbuf,
    unsigned short* __restrict__ vtbuf)
{
    __shared__ unsigned short As[128 * 64];  // [m][k] linear, source-swizzled
    __shared__ unsigned short Bs[128 * 64];  // [n][k] linear, source-swizzled
    const int tid  = threadIdx.x;
    const int lane = tid & 63;
    const int wid  = tid >> 6;
    const int wm = (wid >> 1) * 64, wn = (wid & 1) * 64;
    const int g = lane >> 4, li = lane & 15;
    const int m0 = blockIdx.y * 128;
    const int n0 = blockIdx.x * 128;
    const int srow8 = lane >> 3;             // 0..7
    const int scs8  = (lane & 7) ^ srow8;    // swizzled source slot (16B)

    f32x4 acc[4][4];
    #pragma unroll
    for (int i = 0; i < 4; i++)
        #pragma unroll
        for (int j = 0; j < 4; j++) acc[i][j] = f32x4{0.f, 0.f, 0.f, 0.f};

    for (int k0 = 0; k0 < CDIM; k0 += 64) {
        __syncthreads();
        #pragma unroll
        for (int i = 0; i < 4; i++) {
            int row = wid * 32 + i * 8 + srow8;
            GLOAD_LDS16(&xb[(size_t)(m0 + row) * CDIM + k0 + scs8 * 8],
                        &As[(wid * 32 + i * 8) * 64]);
            GLOAD_LDS16(&wt[(size_t)(n0 + row) * CDIM + k0 + scs8 * 8],
                        &Bs[(wid * 32 + i * 8) * 64]);
        }
        __syncthreads();
        #pragma unroll
        for (int kk = 0; kk < 2; kk++) {
            bf16x8 a[4], b[4];
            #pragma unroll
            for (int mt = 0; mt < 4; mt++) {
                int row = wm + 16 * mt + li;
                a[mt] = *reinterpret_cast<const bf16x8*>(
                    &As[row * 64 + (((4 * kk + g) ^ (li & 7)) * 8)]);
            }
            #pragma unroll
            for (int nt = 0; nt < 4; nt++) {
                int row = wn + 16 * nt + li;
                b[nt] = *reinterpret_cast<const bf16x8*>(
                    &Bs[row * 64 + (((4 * kk + g) ^ (li & 7)) * 8)]);
            }
            #pragma unroll
            for (int mt = 0; mt < 4; mt++)
                #pragma unroll
                for (int nt = 0; nt < 4; nt++)
                    acc[mt][nt] = __builtin_amdgcn_mfma_f32_16x16x32_bf16(
                        a[mt], b[nt], acc[mt][nt], 0, 0, 0);
        }
    }

    #pragma unroll
    for (int mt = 0; mt < 4; mt++) {
        #pragma unroll
        for (int nt = 0; nt < 4; nt++) {
            int col  = n0 + wn + 16 * nt + li;
            int tsel = col / CDIM;
            int rem  = col - tsel * CDIM;
            int h_ = rem >> 6, d = rem & 63;
            float bv = bias[col];
            float sc = (tsel == 0) ? 0.125f : 1.0f;
            #pragma unroll
            for (int r = 0; r < 4; r++) {
                int m  = m0 + wm + 16 * mt + 4 * g + r;
                int b_ = m >> 10, s = m & 1023;
                unsigned short hv = f2bf((acc[mt][nt][r] + bv) * sc);
                if (tsel == 0)
                    qbuf[(((size_t)b_ * NHEAD + h_) * NSEQ + s) * HDIM + d] = hv;
                else if (tsel == 1)
                    kbuf[(((size_t)b_ * NHEAD + h_) * NSEQ + s) * HDIM + d] = hv;
                else
                    vtbuf[(((size_t)b_ * NHEAD + h_) * HDIM + d) * NSEQ + s] = hv;
            }
        }
    }
}

// ---------------------------------------------------------------------------
// Flash-style attention — EXACT round-10 structure (best measured: 46.4 us).
// Async double-buffered K/V via global_load_lds, rule-#21 source-XOR swizzle,
// bias loaded fresh within each phase, Ps padded [16][72]. KVBLK=64.
// ---------------------------------------------------------------------------
__global__ __launch_bounds__(256, 3) void attn_kernel(
    const unsigned short* __restrict__ qbuf,
    const unsigned short* __restrict__ kbuf,
    const unsigned short* __restrict__ vtbuf,
    const float* __restrict__ bias,     // [H,N,N]
    unsigned short* __restrict__ ybuf)  // [B,N,C] bf16
{
    __shared__ unsigned short Kl[2][64 * 64];  // [k][d] linear, source-swizzled
    __shared__ unsigned short Vl[2][64 * 64];  // V^T [d][k] linear, swizzled
    __shared__ unsigned short Ps[4][16][72];   // per-wave P: [q][k]

    const int tid  = threadIdx.x;
    const int lane = tid & 63;
    const int wid  = tid >> 6;
    const int g = lane >> 4, li = lane & 15;
    const int srow8 = lane >> 3;               // 0..7
    const int scs   = (lane & 7) ^ srow8;      // swizzled source slot (16B units)
    const int bh = blockIdx.y;
    const int b_ = bh / NHEAD, h_ = bh % NHEAD;
    const int qw = blockIdx.x * 64 + wid * 16;

    const unsigned short* qb = qbuf + (size_t)bh * NSEQ * HDIM;
    const unsigned short* kb = kbuf + (size_t)bh * NSEQ * HDIM;
    const unsigned short* vb = vtbuf + (size_t)bh * HDIM * NSEQ;
    const float* bb = bias + (size_t)h_ * NSEQ * NSEQ;

#define STAGE_KV(T, KL, VL)                                                    \
    {                                                                          \
        _Pragma("unroll") for (int i = 0; i < 2; i++) {                        \
            GLOAD_LDS16(kb + (size_t)((T) * 64 + wid * 16 + i * 8 + srow8) * HDIM + scs * 8, \
                        (KL) + (wid * 16 + i * 8) * 64);                       \
            GLOAD_LDS16(vb + (size_t)(wid * 16 + i * 8 + srow8) * NSEQ + (T) * 64 + scs * 8, \
                        (VL) + (wid * 16 + i * 8) * 64);                       \
        }                                                                      \
    }

#define COMPUTE_TILE(KS, VS, T)                                                \
    {                                                                          \
        float bv[4][4];                                                        \
        _Pragma("unroll") for (int kt = 0; kt < 4; kt++)                       \
            _Pragma("unroll") for (int r = 0; r < 4; r++)                      \
                bv[kt][r] = bb[(size_t)(qw + 4 * g + r) * NSEQ + (T) * 64 + 16 * kt + li]; \
        f32x4 sacc[4];                                                         \
        _Pragma("unroll") for (int kt = 0; kt < 4; kt++)                       \
            sacc[kt] = f32x4{0.f, 0.f, 0.f, 0.f};                              \
        _Pragma("unroll") for (int kt = 0; kt < 4; kt++)                       \
            _Pragma("unroll") for (int dd = 0; dd < 2; dd++) {                 \
                bf16x8 kf = *reinterpret_cast<const bf16x8*>(                  \
                    (KS) + (16 * kt + li) * 64 + (((4 * dd + g) ^ (li & 7)) * 8)); \
                sacc[kt] = __builtin_amdgcn_mfma_f32_16x16x32_bf16(qf[dd], kf, sacc[kt], 0, 0, 0); \
            }                                                                  \
        _Pragma("unroll") for (int kt = 0; kt < 4; kt++)                       \
            _Pragma("unroll") for (int r = 0; r < 4; r++) {                    \
                float pv = __expf(sacc[kt][r] + bv[kt][r]);                    \
                lpart[r] += pv;                                                \
                Ps[wid][4 * g + r][16 * kt + li] = f2bf(pv);                   \
            }                                                                  \
        _Pragma("unroll") for (int kk = 0; kk < 2; kk++) {                     \
            bf16x8 pf = *reinterpret_cast<const bf16x8*>(&Ps[wid][li][32 * kk + 8 * g]); \
            _Pragma("unroll") for (int dt = 0; dt < 4; dt++) {                 \
                bf16x8 vf = *reinterpret_cast<const bf16x8*>(                  \
                    (VS) + (16 * dt + li) * 64 + (((4 * kk + g) ^ (li & 7)) * 8)); \
                oacc[dt] = __builtin_amdgcn_mfma_f32_16x16x32_bf16(pf, vf, oacc[dt], 0, 0, 0); \
            }                                                                  \
        }                                                                      \
    }

    bf16x8 qf[2];
    #pragma unroll
    for (int dd = 0; dd < 2; dd++)
        qf[dd] = *reinterpret_cast<const bf16x8*>(&qb[(size_t)(qw + li) * HDIM + 32 * dd + 8 * g]);

    f32x4 oacc[4];
    #pragma unroll
    for (int dt = 0; dt < 4; dt++) oacc[dt] = f32x4{0.f, 0.f, 0.f, 0.f};
    float lpart[4] = {0.f, 0.f, 0.f, 0.f};

    STAGE_KV(0, Kl[0], Vl[0]);
    __syncthreads();

    for (int j = 0; j < 8; ++j) {
        const int tA = 2 * j;
        STAGE_KV(tA + 1, Kl[1], Vl[1]);
        COMPUTE_TILE(Kl[0], Vl[0], tA);
        __syncthreads();

        if (j < 7) STAGE_KV(tA + 2, Kl[0], Vl[0]);
        COMPUTE_TILE(Kl[1], Vl[1], tA + 1);
        __syncthreads();
    }

    float linv[4];
    #pragma unroll
    for (int r = 0; r < 4; r++) {
        float s = lpart[r];
        s += __shfl_xor(s, 1);
        s += __shfl_xor(s, 2);
        s += __shfl_xor(s, 4);
        s += __shfl_xor(s, 8);
        linv[r] = 1.f / s;
    }
    #pragma unroll
    for (int dt = 0; dt < 4; dt++)
        #pragma unroll
        for (int r = 0; r < 4; r++) {
            float o = oacc[dt][r] * linv[r];
            int sq = qw + 4 * g + r;
            ybuf[((size_t)b_ * NSEQ + sq) * CDIM + h_ * HDIM + 16 * dt + li] = f2bf(o);
        }
#undef STAGE_KV
#undef COMPUTE_TILE
}

// ---------------------------------------------------------------------------
// Proj GEMM: ybuf [4096,768] bf16 @ pwt [768,768] bf16 (pre-transposed)
// + proj_b -> fp32 out.  BK=64, swizzled staging (same as qkv_gemm).
// ---------------------------------------------------------------------------
__global__ __launch_bounds__(256) void proj_gemm(
    const unsigned short* __restrict__ yb,   // [4096][768]
    const unsigned short* __restrict__ pwt,  // [768][768] (n,k)
    const float* __restrict__ bias, float* __restrict__ out)
{
    __shared__ unsigned short As[128 * 64];
    __shared__ unsigned short Bs[128 * 64];
    const int tid  = threadIdx.x;
    const int lane = tid & 63;
    const int wid  = tid >> 6;
    const int wm = (wid >> 1) * 64, wn = (wid & 1) * 64;
    const int g = lane >> 4, li = lane & 15;
    const int m0 = blockIdx.y * 128;
    const int n0 = blockIdx.x * 128;
    const int srow8 = lane >> 3;
    const int scs8  = (lane & 7) ^ srow8;

    f32x4 acc[4][4];
    #pragma unroll
    for (int i = 0; i < 4; i++)
        #pragma unroll
        for (int j = 0; j < 4; j++) acc[i][j] = f32x4{0.f, 0.f, 0.f, 0.f};

    for (int k0 = 0; k0 < CDIM; k0 += 64) {
        __syncthreads();
        #pragma unroll
        for (int i = 0; i < 4; i++) {
            int row = wid * 32 + i * 8 + srow8;
            GLOAD_LDS16(&yb[(size_t)(m0 + row) * CDIM + k0 + scs8 * 8],
                        &As[(wid * 32 + i * 8) * 64]);
            GLOAD_LDS16(&pwt[(size_t)(n0 + row) * CDIM + k0 + scs8 * 8],
                        &Bs[(wid * 32 + i * 8) * 64]);
        }
        __syncthreads();
        #pragma unroll
        for (int kk = 0; kk < 2; kk++) {
            bf16x8 a[4], b[4];
            #pragma unroll
            for (int mt = 0; mt < 4; mt++) {
                int row = wm + 16 * mt + li;
                a[mt] = *reinterpret_cast<const bf16x8*>(
                    &As[row * 64 + (((4 * kk + g) ^ (li & 7)) * 8)]);
            }
            #pragma unroll
            for (int nt = 0; nt < 4; nt++) {
                int row = wn + 16 * nt + li;
                b[nt] = *reinterpret_cast<const bf16x8*>(
                    &Bs[row * 64 + (((4 * kk + g) ^ (li & 7)) * 8)]);
            }
            #pragma unroll
            for (int mt = 0; mt < 4; mt++)
                #pragma unroll
                for (int nt = 0; nt < 4; nt++)
                    acc[mt][nt] = __builtin_amdgcn_mfma_f32_16x16x32_bf16(
                        a[mt], b[nt], acc[mt][nt], 0, 0, 0);
        }
    }

    #pragma unroll
    for (int mt = 0; mt < 4; mt++)
        #pragma unroll
        for (int nt = 0; nt < 4; nt++) {
            int col = n0 + wn + 16 * nt + li;
            float bv = bias[col];
            #pragma unroll
            for (int r = 0; r < 4; r++) {
                int m = m0 + wm + 16 * mt + 4 * g + r;
                out[(size_t)m * CDIM + col] = acc[mt][nt][r] + bv;
            }
        }
}

extern "C" void kernel_launch(void* const* d_in, const int* in_sizes, int n_in,
                              void* d_out, int out_size, void* d_ws, size_t ws_size,
                              hipStream_t stream) {
    const float* x         = (const float*)d_in[0];
    const float* attn_bias = (const float*)d_in[1];
    const float* qkv_w     = (const float*)d_in[2];
    const float* qkv_b     = (const float*)d_in[3];
    const float* proj_w    = (const float*)d_in[4];
    const float* proj_b    = (const float*)d_in[5];
    float* out = (float*)d_out;

    const size_t per = (size_t)BATCH * NHEAD * NSEQ * HDIM;  // 3,145,728
    unsigned short* qbuf  = (unsigned short*)d_ws;
    unsigned short* kbuf  = qbuf + per;
    unsigned short* vtbuf = kbuf + per;
    unsigned short* xb    = vtbuf + per;
    unsigned short* qwt   = xb + per;                    // [2304][768]
    unsigned short* pwt   = qwt + (size_t)QKVN * CDIM;   // [768][768]
    unsigned short* ybuf  = xb;  // x dead after qkv_gemm

    cvt_f32_bf16<<<(MTOT * CDIM / 4 + 255) / 256, 256, 0, stream>>>(
        x, xb, MTOT * CDIM / 4);
    tcvt_f32_bf16<<<dim3(QKVN / 32, CDIM / 32), 256, 0, stream>>>(
        qkv_w, qwt, CDIM, QKVN);
    tcvt_f32_bf16<<<dim3(CDIM / 32, CDIM / 32), 256, 0, stream>>>(
        proj_w, pwt, CDIM, CDIM);

    qkv_gemm<<<dim3(QKVN / 128, MTOT / 128), 256, 0, stream>>>(
        xb, qwt, qkv_b, qbuf, kbuf, vtbuf);
    attn_kernel<<<dim3(NSEQ / 64, BATCH * NHEAD), 256, 0, stream>>>(
        qbuf, kbuf, vtbuf, attn_bias, ybuf);
    proj_gemm<<<dim3(CDIM / 128, MTOT / 128), 256, 0, stream>>>(
        ybuf, pwt, proj_b, out);
}

// Round 16
// 106.022 us; speedup vs baseline: 1.1458x; 1.0120x over previous
//
#include <hip/hip_runtime.h>
#include <hip/hip_bf16.h>

// Problem constants
constexpr int BATCH = 4;
constexpr int NSEQ  = 1024;
constexpr int CDIM  = 768;
constexpr int NHEAD = 12;
constexpr int HDIM  = 64;
constexpr int MTOT  = BATCH * NSEQ;   // 4096
constexpr int QKVN  = 3 * CDIM;       // 2304

typedef __bf16 bf16x8 __attribute__((ext_vector_type(8)));
typedef float  f32x4  __attribute__((ext_vector_type(4)));

__device__ __forceinline__ unsigned short f2bf(float f) {
    unsigned u = __builtin_bit_cast(unsigned, f);
    unsigned r = u + 0x7FFFu + ((u >> 16) & 1u);   // RNE
    return (unsigned short)(r >> 16);
}

#define GLOAD_LDS16(gp, lp)                                                    \
    __builtin_amdgcn_global_load_lds(                                          \
        (const __attribute__((address_space(1))) void*)(gp),                   \
        (__attribute__((address_space(3))) void*)(lp), 16, 0, 0)

// ---------------------------------------------------------------------------
// Prologue converts
// ---------------------------------------------------------------------------
__global__ __launch_bounds__(256) void cvt_f32_bf16(
    const float* __restrict__ in, unsigned short* __restrict__ out, int n4)
{
    int i = blockIdx.x * 256 + threadIdx.x;
    if (i < n4) {
        float4 a = reinterpret_cast<const float4*>(in)[i];
        ushort4 h;
        h.x = f2bf(a.x); h.y = f2bf(a.y); h.z = f2bf(a.z); h.w = f2bf(a.w);
        reinterpret_cast<ushort4*>(out)[i] = h;
    }
}

// in [R][C] f32  ->  out [C][R] bf16  (32x32 tiles)
__global__ __launch_bounds__(256) void tcvt_f32_bf16(
    const float* __restrict__ in, unsigned short* __restrict__ out, int R, int C)
{
    __shared__ unsigned short t[32][33];
    const int c0 = blockIdx.x * 32, r0 = blockIdx.y * 32;
    const int tc = threadIdx.x & 31, tr = threadIdx.x >> 5;  // tr 0..7
    #pragma unroll
    for (int i = 0; i < 4; i++)
        t[tc][tr + 8 * i] = f2bf(in[(size_t)(r0 + tr + 8 * i) * C + c0 + tc]);
    __syncthreads();
    #pragma unroll
    for (int i = 0; i < 4; i++)
        out[(size_t)(c0 + tr + 8 * i) * R + r0 + tc] = t[tr + 8 * i][tc];
}

// ---------------------------------------------------------------------------
// QKV GEMM: xb [4096,768] bf16 @ wt [2304,768] bf16 (pre-transposed) + bias
// -> scatter bf16 into Q*0.125 [B,H,N,64], K [B,H,N,64], Vt [B,H,64,N]
// Tile 64x128 (grid 1152 = 4.5 blocks/CU, double the TLP of 128x128's 2.25),
// BK=32, 2-phase async double-buffer (r10 attn template): K-step t+1 staged
// via global_load_lds BEFORE computing step t, so the barrier drain lands
// after the compute phase. LDS 2x12KB = 24KB -> capacity 6/CU.
// Wave (wr,wc) = (wid>>1, wid&1): 32 rows x 64 cols -> acc[2][4].
// ---------------------------------------------------------------------------
__global__ __launch_bounds__(256) void qkv_gemm(
    const unsigned short* __restrict__ xb,   // [4096][768]
    const unsigned short* __restrict__ wt,   // [2304][768]
    const float* __restrict__ bias,
    unsigned short* __restrict__ qbuf, unsigned short* __restrict__ kbuf,
    unsigned short* __restrict__ vtbuf)
{
    __shared__ unsigned short A0[64 * 32], A1[64 * 32];
    __shared__ unsigned short B0[128 * 32], B1[128 * 32];
    const int tid  = threadIdx.x;
    const int lane = tid & 63;
    const int wid  = tid >> 6;
    const int wr = (wid >> 1) * 32, wc = (wid & 1) * 64;
    const int g = lane >> 4, li = lane & 15;
    const int m0 = blockIdx.y * 64;
    const int n0 = blockIdx.x * 128;
    const int srow = lane >> 2;          // 0..15
    const int scol = (lane & 3) * 8;     // shorts

#define QSTAGE(K0, AD, BD)                                                     \
    {                                                                          \
        GLOAD_LDS16(&xb[(size_t)(m0 + wid * 16 + srow) * CDIM + (K0) + scol],  \
                    (AD) + wid * 16 * 32);                                     \
        _Pragma("unroll") for (int c = 0; c < 2; c++)                          \
            GLOAD_LDS16(&wt[(size_t)(n0 + wid * 32 + c * 16 + srow) * CDIM + (K0) + scol], \
                        (BD) + (wid * 32 + c * 16) * 32);                      \
    }

#define QCOMPUTE(AS, BS)                                                       \
    {                                                                          \
        bf16x8 a[2], b[4];                                                     \
        _Pragma("unroll") for (int mt = 0; mt < 2; mt++)                       \
            a[mt] = *reinterpret_cast<const bf16x8*>(                          \
                (AS) + (wr + 16 * mt + li) * 32 + 8 * g);                      \
        _Pragma("unroll") for (int nt = 0; nt < 4; nt++)                       \
            b[nt] = *reinterpret_cast<const bf16x8*>(                          \
                (BS) + (wc + 16 * nt + li) * 32 + 8 * g);                      \
        _Pragma("unroll") for (int mt = 0; mt < 2; mt++)                       \
            _Pragma("unroll") for (int nt = 0; nt < 4; nt++)                   \
                acc[mt][nt] = __builtin_amdgcn_mfma_f32_16x16x32_bf16(         \
                    a[mt], b[nt], acc[mt][nt], 0, 0, 0);                       \
    }

    f32x4 acc[2][4];
    #pragma unroll
    for (int i = 0; i < 2; i++)
        #pragma unroll
        for (int j = 0; j < 4; j++) acc[i][j] = f32x4{0.f, 0.f, 0.f, 0.f};

    QSTAGE(0, A0, B0);
    __syncthreads();

    for (int j = 0; j < 12; ++j) {
        const int k0 = j * 64;
        QSTAGE(k0 + 32, A1, B1);
        QCOMPUTE(A0, B0);
        __syncthreads();
        if (j < 11) QSTAGE(k0 + 64, A0, B0);
        QCOMPUTE(A1, B1);
        __syncthreads();
    }

    #pragma unroll
    for (int mt = 0; mt < 2; mt++) {
        #pragma unroll
        for (int nt = 0; nt < 4; nt++) {
            int col  = n0 + wc + 16 * nt + li;
            int tsel = col / CDIM;
            int rem  = col - tsel * CDIM;
            int h_ = rem >> 6, d = rem & 63;
            float bv = bias[col];
            float sc = (tsel == 0) ? 0.125f : 1.0f;
            #pragma unroll
            for (int r = 0; r < 4; r++) {
                int m  = m0 + wr + 16 * mt + 4 * g + r;
                int b_ = m >> 10, s = m & 1023;
                unsigned short hv = f2bf((acc[mt][nt][r] + bv) * sc);
                if (tsel == 0)
                    qbuf[(((size_t)b_ * NHEAD + h_) * NSEQ + s) * HDIM + d] = hv;
                else if (tsel == 1)
                    kbuf[(((size_t)b_ * NHEAD + h_) * NSEQ + s) * HDIM + d] = hv;
                else
                    vtbuf[(((size_t)b_ * NHEAD + h_) * HDIM + d) * NSEQ + s] = hv;
            }
        }
    }
#undef QSTAGE
#undef QCOMPUTE
}

// ---------------------------------------------------------------------------
// Flash-style attention — EXACT round-10 structure (best measured: 46.4 us).
// Async double-buffered K/V via global_load_lds, rule-#21 source-XOR swizzle,
// bias loaded fresh within each phase, Ps padded [16][72]. KVBLK=64.
// ---------------------------------------------------------------------------
__global__ __launch_bounds__(256, 3) void attn_kernel(
    const unsigned short* __restrict__ qbuf,
    const unsigned short* __restrict__ kbuf,
    const unsigned short* __restrict__ vtbuf,
    const float* __restrict__ bias,     // [H,N,N]
    unsigned short* __restrict__ ybuf)  // [B,N,C] bf16
{
    __shared__ unsigned short Kl[2][64 * 64];  // [k][d] linear, source-swizzled
    __shared__ unsigned short Vl[2][64 * 64];  // V^T [d][k] linear, swizzled
    __shared__ unsigned short Ps[4][16][72];   // per-wave P: [q][k]

    const int tid  = threadIdx.x;
    const int lane = tid & 63;
    const int wid  = tid >> 6;
    const int g = lane >> 4, li = lane & 15;
    const int srow8 = lane >> 3;               // 0..7
    const int scs   = (lane & 7) ^ srow8;      // swizzled source slot (16B units)
    const int bh = blockIdx.y;
    const int b_ = bh / NHEAD, h_ = bh % NHEAD;
    const int qw = blockIdx.x * 64 + wid * 16;

    const unsigned short* qb = qbuf + (size_t)bh * NSEQ * HDIM;
    const unsigned short* kb = kbuf + (size_t)bh * NSEQ * HDIM;
    const unsigned short* vb = vtbuf + (size_t)bh * HDIM * NSEQ;
    const float* bb = bias + (size_t)h_ * NSEQ * NSEQ;

#define STAGE_KV(T, KL, VL)                                                    \
    {                                                                          \
        _Pragma("unroll") for (int i = 0; i < 2; i++) {                        \
            GLOAD_LDS16(kb + (size_t)((T) * 64 + wid * 16 + i * 8 + srow8) * HDIM + scs * 8, \
                        (KL) + (wid * 16 + i * 8) * 64);                       \
            GLOAD_LDS16(vb + (size_t)(wid * 16 + i * 8 + srow8) * NSEQ + (T) * 64 + scs * 8, \
                        (VL) + (wid * 16 + i * 8) * 64);                       \
        }                                                                      \
    }

#define COMPUTE_TILE(KS, VS, T)                                                \
    {                                                                          \
        float bv[4][4];                                                        \
        _Pragma("unroll") for (int kt = 0; kt < 4; kt++)                       \
            _Pragma("unroll") for (int r = 0; r < 4; r++)                      \
                bv[kt][r] = bb[(size_t)(qw + 4 * g + r) * NSEQ + (T) * 64 + 16 * kt + li]; \
        f32x4 sacc[4];                                                         \
        _Pragma("unroll") for (int kt = 0; kt < 4; kt++)                       \
            sacc[kt] = f32x4{0.f, 0.f, 0.f, 0.f};                              \
        _Pragma("unroll") for (int kt = 0; kt < 4; kt++)                       \
            _Pragma("unroll") for (int dd = 0; dd < 2; dd++) {                 \
                bf16x8 kf = *reinterpret_cast<const bf16x8*>(                  \
                    (KS) + (16 * kt + li) * 64 + (((4 * dd + g) ^ (li & 7)) * 8)); \
                sacc[kt] = __builtin_amdgcn_mfma_f32_16x16x32_bf16(qf[dd], kf, sacc[kt], 0, 0, 0); \
            }                                                                  \
        _Pragma("unroll") for (int kt = 0; kt < 4; kt++)                       \
            _Pragma("unroll") for (int r = 0; r < 4; r++) {                    \
                float pv = __expf(sacc[kt][r] + bv[kt][r]);                    \
                lpart[r] += pv;                                                \
                Ps[wid][4 * g + r][16 * kt + li] = f2bf(pv);                   \
            }                                                                  \
        _Pragma("unroll") for (int kk = 0; kk < 2; kk++) {                     \
            bf16x8 pf = *reinterpret_cast<const bf16x8*>(&Ps[wid][li][32 * kk + 8 * g]); \
            _Pragma("unroll") for (int dt = 0; dt < 4; dt++) {                 \
                bf16x8 vf = *reinterpret_cast<const bf16x8*>(                  \
                    (VS) + (16 * dt + li) * 64 + (((4 * kk + g) ^ (li & 7)) * 8)); \
                oacc[dt] = __builtin_amdgcn_mfma_f32_16x16x32_bf16(pf, vf, oacc[dt], 0, 0, 0); \
            }                                                                  \
        }                                                                      \
    }

    bf16x8 qf[2];
    #pragma unroll
    for (int dd = 0; dd < 2; dd++)
        qf[dd] = *reinterpret_cast<const bf16x8*>(&qb[(size_t)(qw + li) * HDIM + 32 * dd + 8 * g]);

    f32x4 oacc[4];
    #pragma unroll
    for (int dt = 0; dt < 4; dt++) oacc[dt] = f32x4{0.f, 0.f, 0.f, 0.f};
    float lpart[4] = {0.f, 0.f, 0.f, 0.f};

    STAGE_KV(0, Kl[0], Vl[0]);
    __syncthreads();

    for (int j = 0; j < 8; ++j) {
        const int tA = 2 * j;
        STAGE_KV(tA + 1, Kl[1], Vl[1]);
        COMPUTE_TILE(Kl[0], Vl[0], tA);
        __syncthreads();

        if (j < 7) STAGE_KV(tA + 2, Kl[0], Vl[0]);
        COMPUTE_TILE(Kl[1], Vl[1], tA + 1);
        __syncthreads();
    }

    float linv[4];
    #pragma unroll
    for (int r = 0; r < 4; r++) {
        float s = lpart[r];
        s += __shfl_xor(s, 1);
        s += __shfl_xor(s, 2);
        s += __shfl_xor(s, 4);
        s += __shfl_xor(s, 8);
        linv[r] = 1.f / s;
    }
    #pragma unroll
    for (int dt = 0; dt < 4; dt++)
        #pragma unroll
        for (int r = 0; r < 4; r++) {
            float o = oacc[dt][r] * linv[r];
            int sq = qw + 4 * g + r;
            ybuf[((size_t)b_ * NSEQ + sq) * CDIM + h_ * HDIM + 16 * dt + li] = f2bf(o);
        }
#undef STAGE_KV
#undef COMPUTE_TILE
}

// ---------------------------------------------------------------------------
// Proj GEMM: ybuf [4096,768] bf16 @ pwt [768,768] bf16 (pre-transposed)
// + proj_b -> fp32 out.  Same 64x128 tile + BK=32 + async dbuf as qkv_gemm
// (grid 384 = 1.5 blocks/CU vs 128x128's 0.75).
// ---------------------------------------------------------------------------
__global__ __launch_bounds__(256) void proj_gemm(
    const unsigned short* __restrict__ yb,   // [4096][768]
    const unsigned short* __restrict__ pwt,  // [768][768] (n,k)
    const float* __restrict__ bias, float* __restrict__ out)
{
    __shared__ unsigned short A0[64 * 32], A1[64 * 32];
    __shared__ unsigned short B0[128 * 32], B1[128 * 32];
    const int tid  = threadIdx.x;
    const int lane = tid & 63;
    const int wid  = tid >> 6;
    const int wr = (wid >> 1) * 32, wc = (wid & 1) * 64;
    const int g = lane >> 4, li = lane & 15;
    const int m0 = blockIdx.y * 64;
    const int n0 = blockIdx.x * 128;
    const int srow = lane >> 2;
    const int scol = (lane & 3) * 8;

#define PSTAGE(K0, AD, BD)                                                     \
    {                                                                          \
        GLOAD_LDS16(&yb[(size_t)(m0 + wid * 16 + srow) * CDIM + (K0) + scol],  \
                    (AD) + wid * 16 * 32);                                     \
        _Pragma("unroll") for (int c = 0; c < 2; c++)                          \
            GLOAD_LDS16(&pwt[(size_t)(n0 + wid * 32 + c * 16 + srow) * CDIM + (K0) + scol], \
                        (BD) + (wid * 32 + c * 16) * 32);                      \
    }

#define PCOMPUTE(AS, BS)                                                       \
    {                                                                          \
        bf16x8 a[2], b[4];                                                     \
        _Pragma("unroll") for (int mt = 0; mt < 2; mt++)                       \
            a[mt] = *reinterpret_cast<const bf16x8*>(                          \
                (AS) + (wr + 16 * mt + li) * 32 + 8 * g);                      \
        _Pragma("unroll") for (int nt = 0; nt < 4; nt++)                       \
            b[nt] = *reinterpret_cast<const bf16x8*>(                          \
                (BS) + (wc + 16 * nt + li) * 32 + 8 * g);                      \
        _Pragma("unroll") for (int mt = 0; mt < 2; mt++)                       \
            _Pragma("unroll") for (int nt = 0; nt < 4; nt++)                   \
                acc[mt][nt] = __builtin_amdgcn_mfma_f32_16x16x32_bf16(         \
                    a[mt], b[nt], acc[mt][nt], 0, 0, 0);                       \
    }

    f32x4 acc[2][4];
    #pragma unroll
    for (int i = 0; i < 2; i++)
        #pragma unroll
        for (int j = 0; j < 4; j++) acc[i][j] = f32x4{0.f, 0.f, 0.f, 0.f};

    PSTAGE(0, A0, B0);
    __syncthreads();

    for (int j = 0; j < 12; ++j) {
        const int k0 = j * 64;
        PSTAGE(k0 + 32, A1, B1);
        PCOMPUTE(A0, B0);
        __syncthreads();
        if (j < 11) PSTAGE(k0 + 64, A0, B0);
        PCOMPUTE(A1, B1);
        __syncthreads();
    }

    #pragma unroll
    for (int mt = 0; mt < 2; mt++)
        #pragma unroll
        for (int nt = 0; nt < 4; nt++) {
            int col = n0 + wc + 16 * nt + li;
            float bv = bias[col];
            #pragma unroll
            for (int r = 0; r < 4; r++) {
                int m = m0 + wr + 16 * mt + 4 * g + r;
                out[(size_t)m * CDIM + col] = acc[mt][nt][r] + bv;
            }
        }
#undef PSTAGE
#undef PCOMPUTE
}

extern "C" void kernel_launch(void* const* d_in, const int* in_sizes, int n_in,
                              void* d_out, int out_size, void* d_ws, size_t ws_size,
                              hipStream_t stream) {
    const float* x         = (const float*)d_in[0];
    const float* attn_bias = (const float*)d_in[1];
    const float* qkv_w     = (const float*)d_in[2];
    const float* qkv_b     = (const float*)d_in[3];
    const float* proj_w    = (const float*)d_in[4];
    const float* proj_b    = (const float*)d_in[5];
    float* out = (float*)d_out;

    const size_t per = (size_t)BATCH * NHEAD * NSEQ * HDIM;  // 3,145,728
    unsigned short* qbuf  = (unsigned short*)d_ws;
    unsigned short* kbuf  = qbuf + per;
    unsigned short* vtbuf = kbuf + per;
    unsigned short* xb    = vtbuf + per;
    unsigned short* qwt   = xb + per;                    // [2304][768]
    unsigned short* pwt   = qwt + (size_t)QKVN * CDIM;   // [768][768]
    unsigned short* ybuf  = xb;  // x dead after qkv_gemm

    cvt_f32_bf16<<<(MTOT * CDIM / 4 + 255) / 256, 256, 0, stream>>>(
        x, xb, MTOT * CDIM / 4);
    tcvt_f32_bf16<<<dim3(QKVN / 32, CDIM / 32), 256, 0, stream>>>(
        qkv_w, qwt, CDIM, QKVN);
    tcvt_f32_bf16<<<dim3(CDIM / 32, CDIM / 32), 256, 0, stream>>>(
        proj_w, pwt, CDIM, CDIM);

    qkv_gemm<<<dim3(QKVN / 128, MTOT / 64), 256, 0, stream>>>(
        xb, qwt, qkv_b, qbuf, kbuf, vtbuf);
    attn_kernel<<<dim3(NSEQ / 64, BATCH * NHEAD), 256, 0, stream>>>(
        qbuf, kbuf, vtbuf, attn_bias, ybuf);
    proj_gemm<<<dim3(CDIM / 128, MTOT / 64), 256, 0, stream>>>(
        ybuf, pwt, proj_b, out);
}